// Round 1
// 3098.938 us; speedup vs baseline: 1.2817x; 1.2817x over previous
//
#include <hip/hip_runtime.h>
#include <cmath>
#include <climits>

#define N_ 2048
#define T_ 4096
#define MAXSP 256
#define CHUNK 256
#define NCHUNK (T_ / CHUNK)   // 16

// ---------------- workspace layout (d_ws) ----------------
#define WS_EIDX_OFF   0
#define WS_CNT_OFF    (T_ * 4)
#define WS_SNAP_OFF   (T_ * 4 + NCHUNK * 4)

typedef float f2 __attribute__((ext_vector_type(2)));

__device__ __forceinline__ int imin(int a, int b) { return a < b ? a : b; }

// Raw workgroup barrier with LDS visibility only (no vmcnt drain):
// global prefetches (ic, u_re, w-row) stay in flight across it.
__device__ __forceinline__ void lds_barrier() {
    asm volatile("s_waitcnt lgkmcnt(0)\n\ts_barrier" ::: "memory");
}

// Fill tevents/yevents with +inf, event_types with 0.
__global__ void snn_init_tail(float* __restrict__ out) {
    const size_t base    = (size_t)T_ * N_ * 3;
    const size_t inf_cnt = (size_t)MAXSP + (size_t)MAXSP * N_ * 3;
    const size_t tot     = inf_cnt + (size_t)MAXSP * N_;
    size_t idx = (size_t)blockIdx.x * blockDim.x + threadIdx.x;
    if (idx < tot) {
        out[base + idx] = (idx < inf_cnt) ? __builtin_inff() : 0.0f;
    }
}

// ---------------- Kernel A: sequential scan (1 WG, software-pipelined) ----
extern "C" __global__ void __launch_bounds__(1024)
snn_scan(const float* __restrict__ w,   const float* __restrict__ mu,
         const float* __restrict__ v0,  const float* __restrict__ i0,
         const float* __restrict__ ic,  const float* __restrict__ u_init,
         const float* __restrict__ u_re, float* __restrict__ out,
         int* __restrict__ ws_eidx, int* __restrict__ ws_cnt,
         float* __restrict__ ws_snap)
{
#pragma clang fp contract(off)
    const int tid = threadIdx.x;
    const int n0  = tid * 2;             // two adjacent neurons -> f2 ops
    const int wv  = tid >> 6, lane = tid & 63;
    const float dt = 1.0f / 4096.0f;     // exact: 2^-12
    const float mu1 = mu[0], mu2 = mu[1];

    float* tev = out + (size_t)T_ * N_ * 3;
    float* nsp = tev + MAXSP + (size_t)MAXSP * N_ * 3 + (size_t)MAXSP * N_;

    // pipeline state: (vc,sc) = post-transition state of step k-1;
    // i1p = pre-w i1 of step k-1; (evp,w2) = pending event / w-row load.
    f2 vc, sc, i1p;
    vc  = *(const f2*)(v0 + n0);
    i1p = *(const f2*)(i0 + n0);
    { f2 a = *(const f2*)(u_init + n0);
      sc.x = logf(a.x) - 0.01f; sc.y = logf(a.y) - 0.01f; }  // one-time precise

    bool evp = false;
    f2 w2; w2.x = 0.0f; w2.y = 0.0f;

    // Cross-wave min reduction: single-slot ds_atomic_min per wave +
    // broadcast b32 read. 4-slot rotating buffer; slot (k+2)&3 is reset
    // AFTER the read at iter k — the intervening lds_barrier (lgkmcnt(0)
    // drain before s_barrier) orders the reset against both the prior
    // reads of that slot (iter k-2) and its next atomics (iter k+2).
    __shared__ int red[4];
    if (tid == 0) { red[0] = INT_MAX; red[1] = INT_MAX;
                    red[2] = INT_MAX; red[3] = INT_MAX; }

    // 2-deep prefetch pipeline for ic and u_re
    const float* icp = ic + n0;
    const float* up  = u_re + n0;
    f2 icA = *(const f2*)(icp);
    f2 icB = *(const f2*)(icp + N_);
    f2 uA  = *(const f2*)(up);
    f2 uB  = *(const f2*)(up + N_);
    icp += 2 * N_; up += 2 * N_;

    lds_barrier();   // red[] init visible before first atomics

    int cnt = 0;
#pragma unroll 4
    for (int k = 0; k < T_; ++k) {
        // [1] softplus + mask_k from (vc, sc) — independent of pending w-row.
        // Fast path: for v >= 16, fmax(v,0)+__logf(1+__expf(-v)) rounds to
        // EXACTLY v in fp32 (correction < half-ulp), so both paths are
        // bit-identical; take the transcendental path only if any lane
        // in the wave has v < 16 (wave-uniform branch).
        f2 sp;
        bool slow = (fminf(vc.x, vc.y) < 16.0f);
        if (__ballot(slow)) {
            sp.x = fmaxf(vc.x, 0.0f) + __logf(1.0f + __expf(-fabsf(vc.x)));
            sp.y = fmaxf(vc.y, 0.0f) + __logf(1.0f + __expf(-fabsf(vc.y)));
        } else {
            sp = vc;
        }
        f2 s1 = sc + dt * sp;
        bool m0 = (s1.x >= 0.0f), m1 = (s1.y >= 0.0f);

        // wave candidate, fully scalar: min spiking neuron in this wave is
        // wavebase + min(2*ctz(b0), 2*ctz(b1)+1).  No shfl/ds_bpermute.
        unsigned long long b0 = __ballot(m0);
        unsigned long long b1 = __ballot(b1 == b1 ? m1 : m1); // keep simple
        b1 = __ballot(m1);
        if (b0 | b1) {
            int c0 = b0 ? (((int)__ffsll((long long)b0) - 1) << 1)
                        : INT_MAX;
            int c1 = b1 ? ((((int)__ffsll((long long)b1) - 1) << 1) | 1)
                        : INT_MAX;
            int cand = (wv << 7) + imin(c0, c1);
            if (lane == 0) atomicMin(&red[k & 3], cand);
        }

        // [2] barrier + broadcast read of the single reduction slot
        lds_barrier();
        int eidx = red[k & 3];
        eidx = __builtin_amdgcn_readfirstlane(eidx);   // scalarize
        if (tid == 0) red[(k + 2) & 3] = INT_MAX;      // deferred reset

        // [3] finalize i_{k-1}: waits the pending w[k-1] row load
        f2 ip = i1p;
        if (evp) ip += w2;

        // chunk snapshot: state after step k-1 (= chunk-start state)
        if ((k & (CHUNK - 1)) == 0) {
            const int c = k >> 8;
            float* spn = ws_snap + (size_t)c * 3 * N_;
            *(f2*)(spn + n0)          = vc;
            *(f2*)(spn + N_ + n0)     = ip;
            *(f2*)(spn + 2 * N_ + n0) = sc;
            if (tid == 0) ws_cnt[c] = cnt;
        }

        // [4] Euler for step k — reference op order, no FMA contraction
        f2 v1 = vc + dt * (mu1 * ((ip + icA) - vc));
        i1p   = ip + dt * ((-mu2) * ip);

        // [5]+[6] event handling + per-lane transitions
        evp = (eidx != INT_MAX);
        vc.x = m0 ? (v1.x - 1.0f) : v1.x;
        vc.y = m1 ? (v1.y - 1.0f) : v1.y;
        if (evp) {
            // issue next pending w-row load (waited next iteration at [3])
            w2 = *(const f2*)(w + (size_t)eidx * N_ + n0);
            sc.x = m0 ? (__logf(uA.x) - 0.01f) : s1.x;
            sc.y = m1 ? (__logf(uA.y) - 0.01f) : s1.y;
            if (tid == 0) {
                ws_eidx[k] = eidx;
                if (cnt < MAXSP) tev[cnt] = (float)(k + 1) * dt;
            }
            if (cnt < MAXSP) cnt++;
        } else {
            sc = s1;
            if (tid == 0) ws_eidx[k] = -1;
        }

        // [7] advance 2-deep prefetch
        icA = icB; uA = uB;
        if (k + 2 < T_) {
            icB = *(const f2*)icp;
            uB  = *(const f2*)up;
            icp += N_; up += N_;
        }
    }

    if (tid == 0) nsp[0] = (float)cnt;
}

// ---------------- Kernel B: parallel replay ----------------
extern "C" __global__ void __launch_bounds__(256)
snn_replay(const float* __restrict__ w,   const float* __restrict__ mu,
           const float* __restrict__ ic,  const float* __restrict__ u_re,
           float* __restrict__ out,
           const int* __restrict__ ws_eidx, const int* __restrict__ ws_cnt,
           const float* __restrict__ ws_snap)
{
#pragma clang fp contract(off)
    const int c = blockIdx.x >> 3;                       // chunk
    const int n = ((blockIdx.x & 7) << 8) + threadIdx.x; // neuron
    const float dt = 1.0f / 4096.0f;
    const float mu1 = mu[0], mu2 = mu[1];

    float* ys  = out;
    float* yev = out + (size_t)T_ * N_ * 3 + MAXSP;
    float* et  = yev + (size_t)MAXSP * N_ * 3;

    const float* sp = ws_snap + (size_t)c * 3 * N_;
    float v  = sp[n];
    float ii = sp[N_ + n];
    float ss = sp[2 * N_ + n];
    int cnt = ws_cnt[c];

    const int t0 = c << 8;
    const float* icp = ic + (size_t)t0 * N_ + n;
    const float* up  = u_re + (size_t)t0 * N_ + n;
    float* yr = ys + ((size_t)t0 * N_ + n) * 3;

    for (int k = 0; k < CHUNK; ++k) {
        const int t = t0 + k;
        const int e = ws_eidx[t];          // uniform scalar load
        const float icv = icp[0];

        float v1 = v + dt * (mu1 * ((ii + icv) - v));
        float i1 = ii + dt * ((-mu2) * ii);
        // same bit-exact fast/slow softplus as the scan
        float spv;
        if (__ballot(v < 16.0f)) {
            spv = fmaxf(v, 0.0f) + __logf(1.0f + __expf(-fabsf(v)));
        } else {
            spv = v;
        }
        float s1 = ss + dt * spv;
        bool m = (s1 >= 0.0f);

        if (e >= 0) {                      // event step (uniform branch)
            float wv_ = w[(size_t)e * N_ + n];
            float uu  = up[0];
            if (cnt < MAXSP) {             // record pre-transition state
                float* ye = yev + ((size_t)cnt * N_ + n) * 3;
                ye[0] = v1; ye[1] = i1; ye[2] = s1;
                et[(size_t)cnt * N_ + n] = m ? 1.0f : 0.0f;
                cnt++;
            }
            v  = m ? (v1 - 1.0f) : v1;
            ii = i1 + wv_;
            ss = m ? (__logf(uu) - 0.01f) : s1;
        } else {
            v = v1; ii = i1; ss = s1;
        }

        yr[0] = v; yr[1] = ii; yr[2] = ss;

        icp += N_; up += N_; yr += (size_t)3 * N_;
    }
}

extern "C" void kernel_launch(void* const* d_in, const int* in_sizes, int n_in,
                              void* d_out, int out_size, void* d_ws, size_t ws_size,
                              hipStream_t stream) {
    const float* w      = (const float*)d_in[0];
    const float* mu     = (const float*)d_in[1];
    const float* v0     = (const float*)d_in[2];
    const float* i0     = (const float*)d_in[3];
    const float* ic     = (const float*)d_in[4];
    const float* u_init = (const float*)d_in[5];
    const float* u_re   = (const float*)d_in[6];
    float* out = (float*)d_out;

    char* ws = (char*)d_ws;
    int*   ws_eidx = (int*)(ws + WS_EIDX_OFF);
    int*   ws_cnt  = (int*)(ws + WS_CNT_OFF);
    float* ws_snap = (float*)(ws + WS_SNAP_OFF);

    const size_t tail = (size_t)MAXSP + (size_t)MAXSP * N_ * 3 + (size_t)MAXSP * N_;
    int blocks = (int)((tail + 255) / 256);
    snn_init_tail<<<blocks, 256, 0, stream>>>(out);

    snn_scan<<<1, 1024, 0, stream>>>(w, mu, v0, i0, ic, u_init, u_re,
                                     out, ws_eidx, ws_cnt, ws_snap);

    snn_replay<<<NCHUNK * 8, 256, 0, stream>>>(w, mu, ic, u_re, out,
                                               ws_eidx, ws_cnt, ws_snap);
}